// Round 1
// baseline (204.430 us; speedup 1.0000x reference)
//
#include <hip/hip_runtime.h>
#include <stdint.h>

// Problem constants (fixed by reference setup_inputs)
constexpr int B_ = 8, N_ = 2048, M_ = 2048, K_ = 64;
constexpr int HALF = 1024;  // M tile staged in LDS per phase

// Workspace layout (float offsets). Total ~183K floats (~732 KB).
constexpr int WS_ACC = 0;       // [1]       (unused now; kept for layout stability)
constexpr int WS_MU  = 16;      // [B*9]     per-batch mean of targets
constexpr int WS_S   = 256;     // [B*81]    S = C + C^T (C = pinv(cov))
constexpr int WS_MOM = 1024;    // [B*4*64]  per-block raw-moment partials (9 sum + 45 tri)
constexpr int WS_QB  = 4096;    // [B*N]     qb = 0.5 b^T S b
constexpr int WS_QA  = 20480;   // [B*M]     qa = 0.5 a^T S a
constexpr int WS_U9  = 36864;   // [B*M*9]   u = S a (9 floats/row, 16B-aligned blob)

// ---------------------------------------------------------------------------
// Kernel 1: raw moments per (batch, row-block): Sum(y) [9] and Sum(y y^T) [45]
// Grid (4, B). 512 rows/block, 2 rows/thread, register butterfly reduction,
// per-block output slots (no atomics, no zero-init needed).
// ---------------------------------------------------------------------------
__global__ __launch_bounds__(256) void stats_kernel(const float* __restrict__ targets,
                                                    float* __restrict__ ws)
{
    const int blk = blockIdx.x, b = blockIdx.y, tid = threadIdx.x;
    float s[9], cc[45];
#pragma unroll
    for (int d = 0; d < 9; ++d) s[d] = 0.f;
#pragma unroll
    for (int i = 0; i < 45; ++i) cc[i] = 0.f;

    const float* T = targets + ((size_t)b * M_ + blk * 512) * 9;
#pragma unroll
    for (int r = 0; r < 2; ++r) {
        const float* row = T + (r * 256 + tid) * 9;
        float y[9];
#pragma unroll
        for (int d = 0; d < 9; ++d) { y[d] = row[d]; s[d] += y[d]; }
        int idx = 0;
#pragma unroll
        for (int i = 0; i < 9; ++i)
#pragma unroll
            for (int j = i; j < 9; ++j) { cc[idx] = fmaf(y[i], y[j], cc[idx]); ++idx; }
    }
    // 54 independent butterfly chains (ILP hides swizzle latency)
#pragma unroll
    for (int o = 32; o; o >>= 1) {
#pragma unroll
        for (int d = 0; d < 9; ++d) s[d] += __shfl_xor(s[d], o, 64);
#pragma unroll
        for (int i = 0; i < 45; ++i) cc[i] += __shfl_xor(cc[i], o, 64);
    }
    __shared__ float red[4][54];
    const int wave = tid >> 6, lane = tid & 63;
    if (lane == 0) {
#pragma unroll
        for (int d = 0; d < 9; ++d) red[wave][d] = s[d];
#pragma unroll
        for (int i = 0; i < 45; ++i) red[wave][9 + i] = cc[i];
    }
    __syncthreads();
    if (tid < 54)
        ws[WS_MOM + (b * 4 + blk) * 64 + tid] =
            red[0][tid] + red[1][tid] + red[2][tid] + red[3][tid];
}

// ---------------------------------------------------------------------------
// Kernel 2: per-batch mu, cov (from raw moments), then S = C + C^T with
// C = pinv(cov) = inv(cov^T cov) cov^T via fp64 Gauss-Jordan in LDS.
// ---------------------------------------------------------------------------
__global__ __launch_bounds__(128) void pinv_kernel(float* __restrict__ ws)
{
    __shared__ float smom[64];
    __shared__ double As[81], G[81], Inv[81], Cm[81], fcol[9], smu[9];
    const int b = blockIdx.x, t = threadIdx.x;

    if (t < 54) {
        float v = 0.f;
#pragma unroll
        for (int k = 0; k < 4; ++k) v += ws[WS_MOM + (b * 4 + k) * 64 + t];
        smom[t] = v;
    }
    __syncthreads();
    if (t < 9) {
        const double m = (double)smom[t] / M_;
        smu[t] = m;
        ws[WS_MU + b * 9 + t] = (float)m;
    }
    __syncthreads();
    if (t < 81) {  // cov = Sum(yy^T) - M mu mu^T
        const int i = t / 9, j = t % 9;
        const int ii = i < j ? i : j, jj = i < j ? j : i;
        const int tri = ii * 9 - ii * (ii - 1) / 2 + (jj - ii);
        As[t] = (double)smom[9 + tri] - (double)M_ * smu[i] * smu[j];
    }
    __syncthreads();
    if (t < 81) {
        const int i = t / 9, j = t % 9;
        double sv = 0.0;
#pragma unroll
        for (int k = 0; k < 9; ++k) sv += As[k * 9 + i] * As[k * 9 + j];  // A^T A
        G[t] = sv;
        Inv[t] = (i == j) ? 1.0 : 0.0;
    }
    __syncthreads();

    for (int col = 0; col < 9; ++col) {
        const double p = G[col * 9 + col];  // all read before any write
        __syncthreads();
        if (t < 9) {
            G[col * 9 + t] /= p;
            Inv[col * 9 + t] /= p;
        }
        __syncthreads();
        if (t < 9 && t != col) fcol[t] = G[t * 9 + col];
        __syncthreads();
        if (t < 81) {
            const int r = t / 9, j = t % 9;
            if (r != col) {
                const double f = fcol[r];
                G[t]   -= f * G[col * 9 + j];
                Inv[t] -= f * Inv[col * 9 + j];
            }
        }
        __syncthreads();
    }

    if (t < 81) {  // C = inv(A^T A) A^T
        const int i = t / 9, j = t % 9;
        double sv = 0.0;
#pragma unroll
        for (int k = 0; k < 9; ++k) sv += Inv[i * 9 + k] * As[j * 9 + k];
        Cm[t] = sv;
    }
    __syncthreads();
    if (t < 81) {
        const int i = t / 9, j = t % 9;
        ws[WS_S + b * 81 + t] = (float)(Cm[i * 9 + j] + Cm[j * 9 + i]);  // S = C + C^T
    }
}

// ---------------------------------------------------------------------------
// Kernel 3: U9 rows (u = S a), QA (0.5 a^T S a), QB (0.5 b^T S b); zero out[0]
// (out[0] is the final accumulator now -- topk adds pre-scaled colsums to it).
// ---------------------------------------------------------------------------
__global__ __launch_bounds__(256) void prep_kernel(const float* __restrict__ outputs,
                                                   const float* __restrict__ targets,
                                                   float* __restrict__ ws,
                                                   float* __restrict__ out)
{
    const int gid = blockIdx.x * 256 + threadIdx.x;
    if (gid == 0) out[0] = 0.f;  // stream-ordered before topk's atomics

    if (gid < B_ * M_) {
        const int b = gid >> 11;
        const float* S  = ws + WS_S + b * 81;
        const float* mu = ws + WS_MU + b * 9;
        const float* r  = targets + (size_t)gid * 9;
        float a[9];
#pragma unroll
        for (int d = 0; d < 9; ++d) a[d] = r[d] - mu[d];
        float qa = 0.f;
#pragma unroll
        for (int d = 0; d < 9; ++d) {
            float u = 0.f;
#pragma unroll
            for (int e = 0; e < 9; ++e) u = fmaf(S[d * 9 + e], a[e], u);
            ws[WS_U9 + (size_t)gid * 9 + d] = u;
            qa = fmaf(u, a[d], qa);
        }
        ws[WS_QA + gid] = 0.5f * qa;
    } else if (gid < B_ * (M_ + N_)) {
        const int g2 = gid - B_ * M_;
        const int b = g2 >> 11;
        const float* S = ws + WS_S + b * 81;
        const float* r = outputs + (size_t)g2 * 9;
        float bb[9];
#pragma unroll
        for (int d = 0; d < 9; ++d) bb[d] = r[d];
        float q = 0.f;
#pragma unroll
        for (int d = 0; d < 9; ++d) {
            float v = 0.f;
#pragma unroll
            for (int e = 0; e < 9; ++e) v = fmaf(S[d * 9 + e], bb[e], v);
            q = fmaf(v, bb[d], q);
        }
        ws[WS_QB + g2] = 0.5f * q;
    }
}

// ---------------------------------------------------------------------------
// Kernel 4: sum-of-top-64 per column. 2 columns/wave, M tiled in 2 halves of
// 1024 rows (40 KB LDS: stride-9 rows + qa array, both conflict-free).
// Threshold search: exact monotone-uint binary search over bits 30..8
// (bit 31 is pre-set: quadratic form is PSD, top-64 values are positive).
// Counting uses __ballot + __popcll: one v_cmp per 64 keys on the VALU,
// popcount+accumulate on the parallel SALU pipe, count/threshold/decision all
// wave-uniform SGPRs -- NO cross-lane shuffles in the 23-iteration loop
// (previous version: 24x6 serial ds-swizzle butterflies + cndmask/add chains,
// which left VALUBusy at 49%).
// amdgpu_waves_per_eu(4,4): LDS already caps at 4 blocks/CU, so pin the
// register budget at 128 VGPRs so all 64 live sort keys stay in arch VGPRs
// (previous build allocated only 64 VGPRs chasing 8 waves/EU).
// ---------------------------------------------------------------------------
__global__ __launch_bounds__(256)
__attribute__((amdgpu_waves_per_eu(4, 4)))
void topk_kernel(const float* __restrict__ outputs, float* __restrict__ ws,
                 float* __restrict__ out)
{
    __shared__ float sU[HALF * 9];  // 36864 B
    __shared__ float sQ[HALF];      //  4096 B
    const int b = blockIdx.y;
    const int tid = threadIdx.x;
    const int wave = tid >> 6, lane = tid & 63;
    const int n0 = blockIdx.x * 8 + wave * 2;  // this wave's two columns

    const float* brow = outputs + ((size_t)b * N_ + n0) * 9;
    float ba[9], bb[9];
#pragma unroll
    for (int d = 0; d < 9; ++d) { ba[d] = brow[d]; bb[d] = brow[9 + d]; }

    unsigned ua[32], ub[32];
#pragma unroll
    for (int h = 0; h < 2; ++h) {
        __syncthreads();  // protect LDS from previous phase's readers
        const float4* src = (const float4*)(ws + WS_U9 + ((size_t)b * M_ + h * HALF) * 9);
        float4* dst = (float4*)sU;
#pragma unroll
        for (int i = 0; i < 9; ++i) dst[i * 256 + tid] = src[i * 256 + tid];
        ((float4*)sQ)[tid] = ((const float4*)(ws + WS_QA + (size_t)b * M_ + h * HALF))[tid];
        __syncthreads();

#pragma unroll
        for (int j = 0; j < 16; ++j) {
            const float* r = sU + (j * 64 + lane) * 9;
            const float qa = sQ[j * 64 + lane];
            float aa = qa, ab = qa;
#pragma unroll
            for (int d = 0; d < 9; ++d) {
                const float f = r[d];
                aa = fmaf(-f, ba[d], aa);
                ab = fmaf(-f, bb[d], ab);
            }
            const unsigned xa = __float_as_uint(aa);
            const unsigned xb = __float_as_uint(ab);
            ua[h * 16 + j] = (xa & 0x80000000u) ? ~xa : (xa | 0x80000000u);
            ub[h * 16 + j] = (xb & 0x80000000u) ? ~xb : (xb | 0x80000000u);
        }
    }

    // Binary search for tau (64th largest), bits 30..8. Bit 31 pre-set: keys of
    // non-negative floats all have it, and >=64 of the 2048 distances are
    // positive (PSD quadratic form; top values >> 0). Truncation to 24 bits
    // leaves tau exact to 2^-15 relative -> final-mean bias < 1e-7.
    // Counting: __ballot -> v_cmp (VALU) + s_bcnt1/s_add (SALU, overlapped);
    // cnt/threshold are wave-uniform scalars, no butterflies.
    unsigned ca = 0x80000000u, cb = 0x80000000u;
#pragma unroll 1
    for (int bit = 30; bit >= 8; --bit) {
        const unsigned ta = ca | (1u << bit);
        const unsigned tb = cb | (1u << bit);
        int cnta = 0, cntb = 0;
#pragma unroll
        for (int j = 0; j < 32; ++j) {
            cnta += __popcll(__ballot(ua[j] >= ta));
            cntb += __popcll(__ballot(ub[j] >= tb));
        }
        if (cnta >= K_) ca = ta;
        if (cntb >= K_) cb = tb;
    }

    // Exact sum of strictly-greater values + tie adjustment at tau.
    // g-counts via ballot (wave-uniform); only the float sums need shuffles.
    float sa = 0.f, sb = 0.f;
    int ga = 0, gb = 0;
#pragma unroll
    for (int j = 0; j < 32; ++j) {
        const unsigned va = ua[j], vb = ub[j];
        const float fa = __uint_as_float((va & 0x80000000u) ? (va ^ 0x80000000u) : ~va);
        const float fb = __uint_as_float((vb & 0x80000000u) ? (vb ^ 0x80000000u) : ~vb);
        const bool pa = va > ca, pb = vb > cb;
        sa += pa ? fa : 0.f;
        sb += pb ? fb : 0.f;
        ga += __popcll(__ballot(pa));
        gb += __popcll(__ballot(pb));
    }
#pragma unroll
    for (int o = 32; o; o >>= 1) {
        sa += __shfl_xor(sa, o, 64);
        sb += __shfl_xor(sb, o, 64);
    }

    if (lane == 0) {
        const float tva = __uint_as_float((ca & 0x80000000u) ? (ca ^ 0x80000000u) : ~ca);
        const float tvb = __uint_as_float((cb & 0x80000000u) ? (cb ^ 0x80000000u) : ~cb);
        const float qba = ws[WS_QB + b * N_ + n0];
        const float qbb = ws[WS_QB + b * N_ + n0 + 1];
        const float colsum = sa + (float)(K_ - ga) * tva + (float)K_ * qba
                           + sb + (float)(K_ - gb) * tvb + (float)K_ * qbb;
        // Pre-scale by exact 2^-20 (B*N*K = 2^20): bit-identical to
        // accumulate-then-divide modulo (already nondeterministic) add order.
        atomicAdd(out, colsum * (1.0f / 1048576.0f));
    }
}

// ---------------------------------------------------------------------------
extern "C" void kernel_launch(void* const* d_in, const int* in_sizes, int n_in,
                              void* d_out, int out_size, void* d_ws, size_t ws_size,
                              hipStream_t stream)
{
    (void)in_sizes; (void)n_in; (void)out_size; (void)ws_size;
    const float* outputs = (const float*)d_in[0];  // (B,N,9) fp32
    const float* targets = (const float*)d_in[1];  // (B,M,9) fp32
    float* ws  = (float*)d_ws;
    float* out = (float*)d_out;

    stats_kernel<<<dim3(4, B_), 256, 0, stream>>>(targets, ws);
    pinv_kernel<<<B_, 128, 0, stream>>>(ws);
    prep_kernel<<<(B_ * (M_ + N_)) / 256, 256, 0, stream>>>(outputs, targets, ws, out);
    topk_kernel<<<dim3(N_ / 8, B_), 256, 0, stream>>>(outputs, ws, out);
}